// Round 1
// 886.035 us; speedup vs baseline: 1.1712x; 1.1712x over previous
//
#include <hip/hip_runtime.h>

typedef __attribute__((ext_vector_type(8))) _Float16 half8;
typedef __attribute__((ext_vector_type(4))) float floatx4;

#define NN    10000
#define EE    640000
#define DD    128
#define EDD   64
#define HH    8
#define OUTD  128

__device__ __forceinline__ float fast_rcp(float x) { return __builtin_amdgcn_rcpf(x); }

// load 8 consecutive floats, convert to fp16 fragment
__device__ __forceinline__ half8 cvt8h(const float* __restrict__ p) {
    const floatx4 a = *(const floatx4*)(const void*)p;
    const floatx4 b = *(const floatx4*)(const void*)(p + 4);
    half8 r;
    r[0] = (_Float16)a[0]; r[1] = (_Float16)a[1];
    r[2] = (_Float16)a[2]; r[3] = (_Float16)a[3];
    r[4] = (_Float16)b[0]; r[5] = (_Float16)b[1];
    r[6] = (_Float16)b[2]; r[7] = (_Float16)b[3];
    return r;
}

// edge-index format check: int64 data read as int32 has zero hi-words
__device__ __forceinline__ int idx_is64(const int* __restrict__ eidx) {
    return ((eidx[1] | eidx[3] | eidx[5] | eidx[7]) == 0) ? 1 : 0;
}

// ---------------------------------------------------------------------------
// K0: one-time weight fp32->fp16 preconversion (identical rounding to the
// per-use cvt8h it replaces) + zero sf.  90112 = 352*256 elements exactly.
// w16 layout: [Wq 16384][Wk 16384][W1 16384][W2 16384][Wc 16384][Wre 8192]
// ---------------------------------------------------------------------------
__global__ void __launch_bounds__(256) k_prep(
    const float* __restrict__ Wq, const float* __restrict__ Wk,
    const float* __restrict__ W1, const float* __restrict__ W2,
    const float* __restrict__ Wc, const float* __restrict__ Wre,
    _Float16* __restrict__ w16, float* __restrict__ sf)
{
    const int gid = blockIdx.x * 256 + threadIdx.x;
    float v;
    if (gid < 16384)      v = Wq[gid];
    else if (gid < 32768) v = Wk[gid - 16384];
    else if (gid < 49152) v = W1[gid - 32768];
    else if (gid < 65536) v = W2[gid - 49152];
    else if (gid < 81920) v = Wc[gid - 65536];
    else                  v = Wre[gid - 81920];
    w16[gid] = (_Float16)v;
    if (gid < 80000) sf[gid] = 0.0f;
}

// ---------------------------------------------------------------------------
// K1: node projections q,k and MLP v.  One 16-node tile per block, 8 waves:
// the 24 pre-barrier column units (q/k/mlp1 x 8 col-tiles) are split 3 per
// wave; after the barrier each wave does one mlp2 col-tile.  8x the wave
// count and ~4x shorter per-wave critical chain vs the 1-wave version.
// ---------------------------------------------------------------------------
__global__ void __launch_bounds__(512) k_node(
    const float* __restrict__ h, const _Float16* __restrict__ w16,
    const float* __restrict__ bq, const float* __restrict__ bk,
    const float* __restrict__ b1, const float* __restrict__ b2,
    _Float16* __restrict__ qb, _Float16* __restrict__ kb,
    _Float16* __restrict__ vb)
{
    __shared__ _Float16 L[16 * 136];
    const int wave = threadIdx.x >> 6;
    const int lane = threadIdx.x & 63;
    const int c16 = lane & 15, q4 = lane >> 4;
    const int m0 = blockIdx.x * 16;

    const _Float16* Wq16 = w16;
    const _Float16* Wk16 = w16 + 16384;
    const _Float16* W116 = w16 + 32768;
    const _Float16* W216 = w16 + 49152;

    // A-frags from h rows: A[m=c16][k=q4*8+j], k-steps 0,32,64,96
    const float* hrow = h + (m0 + c16) * DD + q4 * 8;
    half8 af[4];
    af[0] = cvt8h(hrow);
    af[1] = cvt8h(hrow + 32);
    af[2] = cvt8h(hrow + 64);
    af[3] = cvt8h(hrow + 96);

#pragma unroll
    for (int i = 0; i < 3; ++i) {
        const int u = wave * 3 + i;       // 0..23
        const int pass = u >> 3;          // 0=q  1=k  2=mlp1
        const int nt = u & 7;
        const _Float16* W = (pass == 0) ? Wq16 : ((pass == 1) ? Wk16 : W116);
        const float* B    = (pass == 0) ? bq   : ((pass == 1) ? bk   : b1);
        const int col = nt * 16 + c16;
        const float bias = B[col];
        floatx4 acc = {bias, bias, bias, bias};
        const _Float16* wr = W + col * DD + q4 * 8;
#pragma unroll
        for (int s = 0; s < 4; ++s)
            acc = __builtin_amdgcn_mfma_f32_16x16x32_f16(
                af[s], *(const half8*)(const void*)(wr + s * 32), acc, 0, 0, 0);
        if (pass < 2) {
            _Float16* dst = pass ? kb : qb;
#pragma unroll
            for (int r = 0; r < 4; ++r)
                dst[(m0 + q4 * 4 + r) * DD + col] = (_Float16)acc[r];
        } else {
#pragma unroll
            for (int r = 0; r < 4; ++r) {
                const float x = acc[r];
                L[(q4 * 4 + r) * 136 + col] = (_Float16)(x * fast_rcp(1.0f + __expf(-x)));
            }
        }
    }
    __syncthreads();

    // MLP layer 2 -> vb; wave w handles col-tile nt = w
    half8 af2[4];
    const _Float16* l2 = L + c16 * 136 + q4 * 8;
#pragma unroll
    for (int s = 0; s < 4; ++s)
        af2[s] = *(const half8*)(const void*)(l2 + s * 32);
    {
        const int col = wave * 16 + c16;
        const float bias = b2[col];
        floatx4 acc = {bias, bias, bias, bias};
        const _Float16* wr = W216 + col * DD + q4 * 8;
#pragma unroll
        for (int s = 0; s < 4; ++s)
            acc = __builtin_amdgcn_mfma_f32_16x16x32_f16(
                af2[s], *(const half8*)(const void*)(wr + s * 32), acc, 0, 0, 0);
#pragma unroll
        for (int r = 0; r < 4; ++r)
            vb[(m0 + q4 * 4 + r) * DD + col] = (_Float16)acc[r];
    }
}

// ---------------------------------------------------------------------------
// K2: re = silu(t@Wre.T+bre); a = sum_head(q_i*k_j*re); ex=exp(a)->exf;
// atomicAdd into sf[n_i*H+head].  fp16 Wre (no per-wave cvt) + one-iteration
// software prefetch of the scattered q/k fp16 gathers.
// ---------------------------------------------------------------------------
__global__ void __launch_bounds__(256) k_logits(
    const float* __restrict__ t, const int* __restrict__ eidx,
    const _Float16* __restrict__ Wre16, const float* __restrict__ bre,
    const _Float16* __restrict__ qb, const _Float16* __restrict__ kb,
    float* __restrict__ exf, float* __restrict__ sf)
{
    const int wave = threadIdx.x >> 6;
    const int lane = threadIdx.x & 63;
    const int c16 = lane & 15, q4 = lane >> 4;
    const int tile = blockIdx.x * 4 + wave;
    const int m0 = tile * 16;

    const int is64 = idx_is64(eidx);

    // A-frags from t rows (K=64 -> 2 k-steps)
    const float* trow = t + (m0 + c16) * EDD + q4 * 8;
    const half8 a0 = cvt8h(trow);
    const half8 a1 = cvt8h(trow + 32);

    int e_r[4], ni_r[4];
    const _Float16* qrow[4];
    const _Float16* krow[4];
#pragma unroll
    for (int r = 0; r < 4; ++r) {
        const int e = m0 + q4 * 4 + r;
        int nj, ni;
        if (is64) { nj = eidx[2 * e];      ni = eidx[2 * EE + 2 * e]; }
        else      { nj = eidx[e];          ni = eidx[EE + e]; }
        e_r[r] = e; ni_r[r] = ni;
        qrow[r] = qb + ni * DD + c16;
        krow[r] = kb + nj * DD + c16;
    }

    _Float16 qv[4], kv[4], qn[4], kn[4];
#pragma unroll
    for (int r = 0; r < 4; ++r) { qv[r] = qrow[r][0]; kv[r] = krow[r][0]; }

    for (int nt = 0; nt < 8; ++nt) {   // nt == head
        if (nt < 7) {
#pragma unroll
            for (int r = 0; r < 4; ++r) {
                qn[r] = qrow[r][(nt + 1) * 16];
                kn[r] = krow[r][(nt + 1) * 16];
            }
        }
        const int col = nt * 16 + c16;
        const float bias = bre[col];
        floatx4 acc = {bias, bias, bias, bias};
        const _Float16* wr = Wre16 + col * EDD + q4 * 8;
        acc = __builtin_amdgcn_mfma_f32_16x16x32_f16(
            a0, *(const half8*)(const void*)wr, acc, 0, 0, 0);
        acc = __builtin_amdgcn_mfma_f32_16x16x32_f16(
            a1, *(const half8*)(const void*)(wr + 32), acc, 0, 0, 0);

        float part[4];
#pragma unroll
        for (int r = 0; r < 4; ++r) {
            const float x = acc[r];
            const float re = x * fast_rcp(1.0f + __expf(-x));   // silu
            part[r] = re * (float)qv[r] * (float)kv[r];
        }
        // reduce over the 16 lanes of this quad (lane bits 0..3)
        for (int m = 1; m < 16; m <<= 1) {
            part[0] += __shfl_xor(part[0], m, 64);
            part[1] += __shfl_xor(part[1], m, 64);
            part[2] += __shfl_xor(part[2], m, 64);
            part[3] += __shfl_xor(part[3], m, 64);
        }
        if (c16 < 4) {
            const int r = c16;
            const float ex = __expf(part[r]);
            exf[e_r[r] * HH + nt] = ex;
            atomicAdd(&sf[ni_r[r] * HH + nt], ex);
        }
#pragma unroll
        for (int r = 0; r < 4; ++r) { qv[r] = qn[r]; kv[r] = kn[r]; }
    }
}

// ---------------------------------------------------------------------------
// K3: out[e,:] = ((ex/s)*0.25 . v[n_j]) @ Wc.T + bc, fp32 out.
// fp16 Wc (no per-wave cvt of the 64KB weight), per-wave LDS slab with NO
// __syncthreads (waves never share), 2-pass epilogue halves LDS to 17408B
// -> 8 blocks/CU (occupancy 45% -> ~90%).
// ---------------------------------------------------------------------------
__global__ void __launch_bounds__(256, 8) k_out(
    const int* __restrict__ eidx, const float* __restrict__ exf,
    const float* __restrict__ sf, const _Float16* __restrict__ vb,
    const _Float16* __restrict__ Wc16, const float* __restrict__ bc,
    float* __restrict__ outp)
{
    __shared__ float Lf[4][16 * 68];
    const int wave = threadIdx.x >> 6;
    const int lane = threadIdx.x & 63;
    const int c16 = lane & 15, q4 = lane >> 4;
    const int tile = blockIdx.x * 4 + wave;
    const int m0 = tile * 16;

    const int is64 = idx_is64(eidx);

    const int e_a = m0 + c16;         // my A-frag row's edge
    int nj, ni;
    if (is64) { nj = eidx[2 * e_a]; ni = eidx[2 * EE + 2 * e_a]; }
    else      { nj = eidx[e_a];     ni = eidx[EE + e_a]; }

    // A-frags: y[c] = (ex/(s+eps))*0.25 * v[nj][c], c = s*32 + q4*8 + j
    half8 af[4];
#pragma unroll
    for (int s = 0; s < 4; ++s) {
        const int h0 = s * 2 + (q4 >> 1);            // head, uniform per (s,q4)
        const float exv = exf[e_a * HH + h0];
        const float sv = sf[ni * HH + h0];
        const float asc = exv * fast_rcp(sv + 1e-16f) * 0.25f;
        const half8 v8 = *(const half8*)(const void*)(vb + nj * DD + s * 32 + q4 * 8);
        half8 y;
#pragma unroll
        for (int j = 0; j < 8; ++j)
            y[j] = (_Float16)((float)v8[j] * asc);
        af[s] = y;
    }

    floatx4 acc[8];
#pragma unroll
    for (int nt = 0; nt < 8; ++nt) {
        const int col = nt * 16 + c16;
        const float bias = bc[col];
        acc[nt] = (floatx4){bias, bias, bias, bias};
        const _Float16* wr = Wc16 + col * DD + q4 * 8;
#pragma unroll
        for (int s = 0; s < 4; ++s)
            acc[nt] = __builtin_amdgcn_mfma_f32_16x16x32_f16(
                af[s], *(const half8*)(const void*)(wr + s * 32), acc[nt], 0, 0, 0);
    }

    // per-wave LDS slab, two 64-column passes; wave-internal only, so no
    // barrier needed (compiler inserts the lgkmcnt waits).
    float* Lw = Lf[wave];
    float* ob = outp + (size_t)m0 * OUTD;   // 16 rows x 512B contiguous
#pragma unroll
    for (int p = 0; p < 2; ++p) {
#pragma unroll
        for (int j = 0; j < 4; ++j)
#pragma unroll
            for (int r = 0; r < 4; ++r)
                Lw[(q4 * 4 + r) * 68 + j * 16 + c16] = acc[p * 4 + j][r];
#pragma unroll
        for (int tt = 0; tt < 4; ++tt) {
            const int idx = tt * 64 + lane;      // float4-chunk id, 0..255
            const int row = idx >> 4;            // 16 chunks per 64-col row
            const int c4 = (idx & 15) * 4;
            const floatx4 val = *(const floatx4*)(const void*)&Lw[row * 68 + c4];
            *(floatx4*)(void*)(ob + row * OUTD + p * 64 + c4) = val;
        }
    }
}

// ---------------------------------------------------------------------------
extern "C" void kernel_launch(void* const* d_in, const int* in_sizes, int n_in,
                              void* d_out, int out_size, void* d_ws, size_t ws_size,
                              hipStream_t stream) {
    (void)in_sizes; (void)n_in; (void)out_size; (void)ws_size;
    const float* h   = (const float*)d_in[0];
    const float* t   = (const float*)d_in[1];
    const int*   eidx= (const int*)d_in[2];
    const float* Wq  = (const float*)d_in[3];
    const float* bq  = (const float*)d_in[4];
    const float* Wk  = (const float*)d_in[5];
    const float* bk  = (const float*)d_in[6];
    const float* W1  = (const float*)d_in[7];
    const float* b1  = (const float*)d_in[8];
    const float* W2  = (const float*)d_in[9];
    const float* b2  = (const float*)d_in[10];
    const float* Wre = (const float*)d_in[11];
    const float* bre = (const float*)d_in[12];
    const float* Wc  = (const float*)d_in[13];
    const float* bc  = (const float*)d_in[14];
    float* out = (float*)d_out;

    char* ws = (char*)d_ws;
    _Float16* qb = (_Float16*)(ws);                // N*128 fp16 = 2,560,000 B
    _Float16* kb = (_Float16*)(ws + 2560000);
    _Float16* vb = (_Float16*)(ws + 5120000);
    float*    exf= (float*)   (ws + 7680000);      // E*8 f32 = 20,480,000 B
    float*    sf = (float*)   (ws + 28160000);     // N*8 f32 = 320,000 B
    _Float16* w16= (_Float16*)(ws + 28480000);     // 90112 fp16 = 180,224 B

    k_prep<<<dim3(352), dim3(256), 0, stream>>>(Wq, Wk, W1, W2, Wc, Wre, w16, sf);
    k_node<<<dim3(625), dim3(512), 0, stream>>>(h, w16, bq, bk, b1, b2, qb, kb, vb);
    k_logits<<<dim3(10000), dim3(256), 0, stream>>>(t, eidx, w16 + 81920, bre, qb, kb, exf, sf);
    k_out<<<dim3(10000), dim3(256), 0, stream>>>(eidx, exf, sf, vb, w16 + 65536, bc, out);
}